// Round 4
// baseline (192834.924 us; speedup 1.0000x reference)
//
#include <hip/hip_runtime.h>

#define B_   128
#define T_   128
#define E_   1024
#define NH_  8
#define G_   3072
#define QK_  512
#define SCALE_ 0.125f
#define NB   512
#define NT   256

// ---------------------------------------------------------------------------
// JAX Threefry-2x32-20 (bit-exact) + XLA f32 erfinv path  (verified R2/R3)
// ---------------------------------------------------------------------------
__device__ __forceinline__ unsigned rotl32(unsigned x, int r) {
  return (x << r) | (x >> (32 - r));
}

__device__ __forceinline__ void tf2x32(unsigned k0, unsigned k1,
                                       unsigned x0, unsigned x1,
                                       unsigned& o0, unsigned& o1) {
  unsigned k2 = k0 ^ k1 ^ 0x1BD11BDAu;
  x0 += k0; x1 += k1;
  x0 += x1; x1 = rotl32(x1, 13); x1 ^= x0;
  x0 += x1; x1 = rotl32(x1, 15); x1 ^= x0;
  x0 += x1; x1 = rotl32(x1, 26); x1 ^= x0;
  x0 += x1; x1 = rotl32(x1,  6); x1 ^= x0;
  x0 += k1; x1 += k2 + 1u;
  x0 += x1; x1 = rotl32(x1, 17); x1 ^= x0;
  x0 += x1; x1 = rotl32(x1, 29); x1 ^= x0;
  x0 += x1; x1 = rotl32(x1, 16); x1 ^= x0;
  x0 += x1; x1 = rotl32(x1, 24); x1 ^= x0;
  x0 += k2; x1 += k0 + 2u;
  x0 += x1; x1 = rotl32(x1, 13); x1 ^= x0;
  x0 += x1; x1 = rotl32(x1, 15); x1 ^= x0;
  x0 += x1; x1 = rotl32(x1, 26); x1 ^= x0;
  x0 += x1; x1 = rotl32(x1,  6); x1 ^= x0;
  x0 += k0; x1 += k1 + 3u;
  x0 += x1; x1 = rotl32(x1, 17); x1 ^= x0;
  x0 += x1; x1 = rotl32(x1, 29); x1 ^= x0;
  x0 += x1; x1 = rotl32(x1, 16); x1 ^= x0;
  x0 += x1; x1 = rotl32(x1, 24); x1 ^= x0;
  x0 += k1; x1 += k2 + 4u;
  x0 += x1; x1 = rotl32(x1, 13); x1 ^= x0;
  x0 += x1; x1 = rotl32(x1, 15); x1 ^= x0;
  x0 += x1; x1 = rotl32(x1, 26); x1 ^= x0;
  x0 += x1; x1 = rotl32(x1,  6); x1 ^= x0;
  x0 += k2; x1 += k0 + 5u;
  o0 = x0; o1 = x1;
}

__device__ __forceinline__ float bits_to_normal(unsigned bits) {
  float uf = __uint_as_float((bits >> 9) | 0x3F800000u) - 1.0f;
  const float LO = -0.99999994f;
  float u = fmaxf(LO, uf * 2.0f + LO);
  float w = -log1pf(-u * u);
  float p;
  if (w < 5.0f) {
    w -= 2.5f;
    p = 2.81022636e-08f;
    p = fmaf(p, w, 3.43273939e-07f);
    p = fmaf(p, w, -3.5233877e-06f);
    p = fmaf(p, w, -4.39150654e-06f);
    p = fmaf(p, w, 0.00021858087f);
    p = fmaf(p, w, -0.00125372503f);
    p = fmaf(p, w, -0.00417768164f);
    p = fmaf(p, w, 0.246640727f);
    p = fmaf(p, w, 1.50140941f);
  } else {
    w = sqrtf(w) - 3.0f;
    p = -0.000200214257f;
    p = fmaf(p, w, 0.000100950558f);
    p = fmaf(p, w, 0.00134934322f);
    p = fmaf(p, w, -0.00367342844f);
    p = fmaf(p, w, 0.00573950773f);
    p = fmaf(p, w, -0.0076224613f);
    p = fmaf(p, w, 0.00943887047f);
    p = fmaf(p, w, 1.00167406f);
    p = fmaf(p, w, 2.83297682f);
  }
  return 1.41421356f * p * u;
}

__device__ __forceinline__ float4 gen4(unsigned k0, unsigned k1, unsigned f) {
  unsigned o0, o1; float4 n;
  tf2x32(k0, k1, 0u, f + 0u, o0, o1); n.x = bits_to_normal(o0 ^ o1);
  tf2x32(k0, k1, 0u, f + 1u, o0, o1); n.y = bits_to_normal(o0 ^ o1);
  tf2x32(k0, k1, 0u, f + 2u, o0, o1); n.z = bits_to_normal(o0 ^ o1);
  tf2x32(k0, k1, 0u, f + 3u, o0, o1); n.w = bits_to_normal(o0 ^ o1);
  return n;
}

__device__ __forceinline__ float sigmoidf_(float x) {
  return 1.0f / (1.0f + expf(-x));
}

__device__ __forceinline__ float4 f4add(float4 a, float4 b) {
  a.x += b.x; a.y += b.y; a.z += b.z; a.w += b.w; return a;
}

__device__ __forceinline__ float ld_elem(const void* p, long i, int isb) {
  if (isb) {
    unsigned short u = ((const unsigned short*)p)[i];
    return __uint_as_float(((unsigned)u) << 16);
  }
  return ((const float*)p)[i];
}

// ---------------------------------------------------------------------------
// prep kernels (verified R3 lineage)
// ---------------------------------------------------------------------------
__global__ __launch_bounds__(256) void sniff_kernel(const void* encs, int* flag) {
  __shared__ int cnt;
  if (threadIdx.x == 0) cnt = 0;
  __syncthreads();
  const unsigned* w = (const unsigned*)encs;
  int c = 0;
  for (int i = threadIdx.x; i < 4096; i += 256) {
    unsigned e7 = (w[i] >> 8) & 0x7F;
    if (e7 >= 0x3B && e7 <= 0x41) c++;
  }
  atomicAdd(&cnt, c);
  __syncthreads();
  if (threadIdx.x == 0) flag[0] = (cnt > 2048) ? 1 : 0;
}

__global__ __launch_bounds__(256) void conv_kernel(const void* src, float* dst,
                                                   long n, const int* flag) {
  long i = (long)blockIdx.x * 256 + threadIdx.x;
  int isb = flag[0];
  if (i < n) dst[i] = ld_elem(src, i, isb);
}

__global__ __launch_bounds__(256) void trans_kernel(
    const void* W_ih, const void* W_hh, const void* W_mu, const void* W_sig,
    const void* W_k, const float* __restrict__ bihF, const float* __restrict__ bhhF,
    float* __restrict__ Wbig, float* __restrict__ Wms, float* __restrict__ WkT,
    float* __restrict__ Wenc4, float* __restrict__ bias4,
    float* __restrict__ hbuf, unsigned* __restrict__ skeys, unsigned* bar,
    const int* flag)
{
  long idx = (long)blockIdx.x * 256 + threadIdx.x;
  int y = blockIdx.y;
  int isb = flag[0];
  if (y == 0) {                       // Wbig ctx rows (0..1023), interleaved-4 cols
    if (idx < 4194304) {
      int e = (int)(idx & 1023); int col = (int)(idx >> 10);
      int j = col >> 2, c = col & 3;
      float v = 0.f;
      if (c < 3) v = ld_elem(W_ih, (long)(c * 1024 + j) * 2048 + 1024 + e, isb);
      Wbig[(long)e * 4096 + col] = v;
    }
  } else if (y == 1) {                // Wbig h rows (1024..2047)
    if (idx < 4194304) {
      int e = (int)(idx & 1023); int col = (int)(idx >> 10);
      int j = col >> 2, c = col & 3;
      float v = 0.f;
      if (c == 0)      v = ld_elem(W_hh, (long)j * 1024 + e, isb);
      else if (c == 1) v = ld_elem(W_hh, (long)(1024 + j) * 1024 + e, isb);
      else if (c == 3) v = ld_elem(W_hh, (long)(2048 + j) * 1024 + e, isb);
      Wbig[(long)(1024 + e) * 4096 + col] = v;
    }
  } else if (y == 2) {                // Wms
    if (idx < 2097152) {
      int k = (int)(idx >> 11), n = (int)(idx & 2047);
      float v = (n < 1024) ? ld_elem(W_mu, (long)k * 1024 + n, isb)
                           : ld_elem(W_sig, (long)k * 1024 + (n - 1024), isb);
      Wms[idx] = v;
    }
  } else if (y == 3) {                // WkT + bias4 + zero hbuf + skeys + bar
    if (idx < 524288) {
      int qk = (int)(idx >> 10), e = (int)(idx & 1023);
      WkT[idx] = ld_elem(W_k, (long)e * 512 + qk, isb);
    }
    if (idx < 4096) {
      int j = (int)(idx >> 2), c = (int)(idx & 3);
      float v;
      if (c == 0)      v = bihF[j] + bhhF[j];
      else if (c == 1) v = bihF[1024 + j] + bhhF[1024 + j];
      else if (c == 2) v = bihF[2048 + j];
      else             v = bhhF[2048 + j];
      bias4[idx] = v;
    }
    if (idx < 131072) hbuf[idx] = 0.f;
    if (idx < 128) {
      unsigned o0, o1;
      tf2x32(0u, 1234u, 0u, (unsigned)idx, o0, o1);
      skeys[2 * idx] = o0; skeys[2 * idx + 1] = o1;
    }
    if (idx == 0) bar[0] = 0u;
  } else {                            // Wenc4
    if (idx < 4194304) {
      int e = (int)(idx & 1023); int col = (int)(idx >> 10);
      int j = col >> 2, c = col & 3;
      float v = 0.f;
      if (c < 3) v = ld_elem(W_ih, (long)(c * 1024 + j) * 2048 + e, isb);
      Wenc4[(long)e * 4096 + col] = v;
    }
  }
}

__global__ __launch_bounds__(256) void consts_kernel(
    const float* __restrict__ bqF, const float* __restrict__ bkF,
    const float* __restrict__ bvF, const float* __restrict__ boF,
    const float* __restrict__ WkT, const float* __restrict__ WoF,
    float* __restrict__ bqk, float* __restrict__ qbc, float* __restrict__ bvo)
{
  int idx = blockIdx.x * 256 + threadIdx.x;  // < 8192
  int hh = idx >> 10, e = idx & 1023;
  float s = 0.f;
  for (int a = 0; a < 64; ++a)
    s += bqF[hh * 64 + a] * WkT[(long)(hh * 64 + a) * 1024 + e];
  bqk[idx] = s;
  if (idx < 1024) {
    float v = boF[idx];
    for (int ha = 0; ha < 512; ++ha) v += bvF[ha] * WoF[(long)ha * 1024 + idx];
    bvo[idx] = v;
  }
  if (idx < 8) {
    float v = 0.f;
    for (int a = 0; a < 64; ++a) v += bqF[idx * 64 + a] * bkF[idx * 64 + a];
    qbc[idx] = v;
  }
}

// generic 128x128 GEMM (R3-verified) — used once for gie4
__global__ __launch_bounds__(256) void mm128(
    const float* __restrict__ A, long lda,
    const float* __restrict__ Bm, long ldb,
    float* __restrict__ C, long ldc, int Ktot)
{
  long m0 = (long)blockIdx.y * 128;
  long n0 = (long)blockIdx.x * 128;
  __shared__ float As[16][132];
  __shared__ float Bs[16][132];
  int tid = threadIdx.x;
  int tx = tid & 15, ty = tid >> 4;
  int am = tid >> 2, ac = tid & 3;
  int bk = tid >> 5, bn = tid & 31;
  float acc[8][8];
  #pragma unroll
  for (int i = 0; i < 8; ++i)
    #pragma unroll
    for (int j = 0; j < 8; ++j) acc[i][j] = 0.f;
  for (int k0 = 0; k0 < Ktot; k0 += 16) {
    float4 a0 = *(const float4*)(A + (m0 + am) * lda + k0 + 4 * ac);
    float4 a1 = *(const float4*)(A + (m0 + am + 64) * lda + k0 + 4 * ac);
    float4 b0 = *(const float4*)(Bm + (long)(k0 + bk) * ldb + n0 + 4 * bn);
    float4 b1 = *(const float4*)(Bm + (long)(k0 + bk + 8) * ldb + n0 + 4 * bn);
    __syncthreads();
    As[4 * ac + 0][am] = a0.x; As[4 * ac + 1][am] = a0.y;
    As[4 * ac + 2][am] = a0.z; As[4 * ac + 3][am] = a0.w;
    As[4 * ac + 0][am + 64] = a1.x; As[4 * ac + 1][am + 64] = a1.y;
    As[4 * ac + 2][am + 64] = a1.z; As[4 * ac + 3][am + 64] = a1.w;
    *(float4*)&Bs[bk][4 * bn] = b0;
    *(float4*)&Bs[bk + 8][4 * bn] = b1;
    __syncthreads();
    #pragma unroll
    for (int kk = 0; kk < 16; ++kk) {
      float4 av0 = *(const float4*)&As[kk][ty * 4];
      float4 av1 = *(const float4*)&As[kk][64 + ty * 4];
      float4 bv0 = *(const float4*)&Bs[kk][tx * 4];
      float4 bv1 = *(const float4*)&Bs[kk][64 + tx * 4];
      float amv[8] = {av0.x, av0.y, av0.z, av0.w, av1.x, av1.y, av1.z, av1.w};
      float bnv[8] = {bv0.x, bv0.y, bv0.z, bv0.w, bv1.x, bv1.y, bv1.z, bv1.w};
      #pragma unroll
      for (int i = 0; i < 8; ++i)
        #pragma unroll
        for (int j = 0; j < 8; ++j)
          acc[i][j] = fmaf(amv[i], bnv[j], acc[i][j]);
    }
  }
  #pragma unroll
  for (int i = 0; i < 8; ++i) {
    long r = m0 + (long)(i >> 2) * 64 + ty * 4 + (i & 3);
    float4 v0 = {acc[i][0], acc[i][1], acc[i][2], acc[i][3]};
    float4 v1 = {acc[i][4], acc[i][5], acc[i][6], acc[i][7]};
    *(float4*)(C + r * ldc + n0 + tx * 4) = v0;
    *(float4*)(C + r * ldc + n0 + 64 + tx * 4) = v1;
  }
}

// ---------------------------------------------------------------------------
// persistent scan kernel
// ---------------------------------------------------------------------------
struct SArgs {
  const float *Wbig, *Wms, *WkT, *Wq, *Wv, *Wo;
  const float *gie4, *bias4, *bqk, *qbc, *bvo, *bmu, *bsig, *bk;
  const unsigned *skeys;
  float *hbuf, *gsumP, *musigP, *qP, *tmat, *qbv, *scg, *ctxE, *ctxhP, *ctxvP;
  float *mus, *sigs, *s;
  unsigned *bar;
};

__device__ __forceinline__ void gridbar(unsigned* bar, unsigned& bcnt) {
  __syncthreads();   // drains this block's stores (compiler emits vmcnt(0))
  if (threadIdx.x == 0) {
    __hip_atomic_fetch_add(bar, 1u, __ATOMIC_RELEASE, __HIP_MEMORY_SCOPE_AGENT);
    unsigned tgt = (bcnt + 1u) * (unsigned)NB;
    while (__hip_atomic_load(bar, __ATOMIC_ACQUIRE, __HIP_MEMORY_SCOPE_AGENT) < tgt)
      __builtin_amdgcn_s_sleep(1);
  }
  bcnt++;
  __syncthreads();
  __threadfence();   // all threads: acquire-invalidate L1
}

__global__ __launch_bounds__(NT, 2) void scan_kernel(SArgs a) {
  __shared__ float lds[5280];
  const int bid = blockIdx.x, tid = threadIdx.x;
  const int gtid = bid * NT + tid;
  const int tx = tid & 15, ty = tid >> 4;
  unsigned bcnt = 0;

  #pragma clang loop unroll(disable)
  for (int step = 0; step < T_; ++step) {
    const unsigned sk0 = a.skeys[2 * step], sk1 = a.skeys[2 * step + 1];

    // ============ P1: G1 (xh@Wbig, split-16) + gen_old ============
    {
      float* As = lds;          // [16][132]
      float* Bs = lds + 2112;   // [16][132]
      int nt = bid >> 4, sp = bid & 15;
      int kbase = sp << 7;      // Kc=128
      int am = tid >> 2, ac = tid & 3;
      int bk2 = tid >> 5, bn = tid & 31;
      float acc[8][8];
      #pragma unroll
      for (int i = 0; i < 8; ++i)
        #pragma unroll
        for (int j = 0; j < 8; ++j) acc[i][j] = 0.f;
      for (int c = 0; c < 8; ++c) {
        int kc = kbase + (c << 4);
        int k = kc + (ac << 2);
        float4 a0, a1;
        if (sp < 8) {           // ctx region: sum 4 O-partials + bvo (0 at step 0)
          if (step == 0) {
            a0.x = a0.y = a0.z = a0.w = 0.f; a1 = a0;
          } else {
            a0 = *(const float4*)(a.bvo + k);
            a1 = a0;
            #pragma unroll
            for (int s2 = 0; s2 < 4; ++s2) {
              a0 = f4add(a0, *(const float4*)(a.ctxvP + s2 * 131072 + am * 1024 + k));
              a1 = f4add(a1, *(const float4*)(a.ctxvP + s2 * 131072 + (am + 64) * 1024 + k));
            }
          }
        } else {                // h region
          a0 = *(const float4*)(a.hbuf + am * 1024 + (k - 1024));
          a1 = *(const float4*)(a.hbuf + (am + 64) * 1024 + (k - 1024));
        }
        float4 b0 = *(const float4*)(a.Wbig + (long)(kc + bk2) * 4096 + (nt << 7) + (bn << 2));
        float4 b1 = *(const float4*)(a.Wbig + (long)(kc + bk2 + 8) * 4096 + (nt << 7) + (bn << 2));
        __syncthreads();
        As[(4 * ac + 0) * 132 + am] = a0.x; As[(4 * ac + 1) * 132 + am] = a0.y;
        As[(4 * ac + 2) * 132 + am] = a0.z; As[(4 * ac + 3) * 132 + am] = a0.w;
        As[(4 * ac + 0) * 132 + am + 64] = a1.x; As[(4 * ac + 1) * 132 + am + 64] = a1.y;
        As[(4 * ac + 2) * 132 + am + 64] = a1.z; As[(4 * ac + 3) * 132 + am + 64] = a1.w;
        *(float4*)&Bs[bk2 * 132 + (bn << 2)] = b0;
        *(float4*)&Bs[(bk2 + 8) * 132 + (bn << 2)] = b1;
        __syncthreads();
        #pragma unroll
        for (int kk = 0; kk < 16; ++kk) {
          float4 av0 = *(const float4*)&As[kk * 132 + ty * 4];
          float4 av1 = *(const float4*)&As[kk * 132 + 64 + ty * 4];
          float4 bv0 = *(const float4*)&Bs[kk * 132 + tx * 4];
          float4 bv1 = *(const float4*)&Bs[kk * 132 + 64 + tx * 4];
          float amv[8] = {av0.x, av0.y, av0.z, av0.w, av1.x, av1.y, av1.z, av1.w};
          float bnv[8] = {bv0.x, bv0.y, bv0.z, bv0.w, bv1.x, bv1.y, bv1.z, bv1.w};
          #pragma unroll
          for (int i = 0; i < 8; ++i)
            #pragma unroll
            for (int j = 0; j < 8; ++j)
              acc[i][j] = fmaf(amv[i], bnv[j], acc[i][j]);
        }
      }
      #pragma unroll
      for (int i = 0; i < 8; ++i) {
        int r = ((i >> 2) << 6) + ty * 4 + (i & 3);
        float4 v0 = {acc[i][0], acc[i][1], acc[i][2], acc[i][3]};
        float4 v1 = {acc[i][4], acc[i][5], acc[i][6], acc[i][7]};
        *(float4*)(a.gsumP + sp * 524288 + (long)r * 4096 + (nt << 7) + tx * 4) = v0;
        *(float4*)(a.gsumP + sp * 524288 + (long)r * 4096 + (nt << 7) + 64 + tx * 4) = v1;
      }
      // gen_old: re-noise rows 0..step-1 with this step's key
      int njobs = step << 15;  // step * 32768 float4 jobs
      for (int jdx = gtid; jdx < njobs; jdx += NB * NT) {
        int t = jdx >> 15;
        int b = (jdx >> 8) & 127;
        int e = (jdx & 255) << 2;
        long off = (long)b * 131072 + (long)t * 1024 + e;
        float4 n4 = gen4(sk0, sk1, (unsigned)off);
        float4 mu = *(const float4*)(a.mus + off);
        float4 sg = *(const float4*)(a.sigs + off);
        float4 out;
        out.x = fmaf(n4.x, sg.x, mu.x); out.y = fmaf(n4.y, sg.y, mu.y);
        out.z = fmaf(n4.z, sg.z, mu.z); out.w = fmaf(n4.w, sg.w, mu.w);
        *(float4*)(a.s + off) = out;
      }
    }
    gridbar(a.bar, bcnt);

    // ============ P2: GRU combine ============
    {
      int b = gtid >> 10, jj = gtid & 1023;
      float4 v = ((const float4*)a.gie4)[b * 1024 + jj];
      v = f4add(v, ((const float4*)a.bias4)[jj]);
      #pragma unroll
      for (int s2 = 0; s2 < 16; ++s2)
        v = f4add(v, ((const float4*)a.gsumP)[s2 * 131072 + b * 1024 + jj]);
      float r = sigmoidf_(v.x), z = sigmoidf_(v.y);
      float n = tanhf(v.z + r * v.w);
      int idx = b * 1024 + jj;
      a.hbuf[idx] = (1.f - z) * n + z * a.hbuf[idx];
    }
    gridbar(a.bar, bcnt);

    // ============ P3: G2 (h@Wms, split-16) ============
    if (bid < 256) {
      float* As = lds;          // [16][132]
      float* Bs = lds + 2112;
      int nt = bid >> 4, sp = bid & 15;
      int kbase = sp << 6;      // Kc=64
      int am = tid >> 2, ac = tid & 3;
      int bk2 = tid >> 5, bn = tid & 31;
      float acc[8][8];
      #pragma unroll
      for (int i = 0; i < 8; ++i)
        #pragma unroll
        for (int j = 0; j < 8; ++j) acc[i][j] = 0.f;
      for (int c = 0; c < 4; ++c) {
        int kc = kbase + (c << 4);
        int k = kc + (ac << 2);
        float4 a0 = *(const float4*)(a.hbuf + am * 1024 + k);
        float4 a1 = *(const float4*)(a.hbuf + (am + 64) * 1024 + k);
        float4 b0 = *(const float4*)(a.Wms + (long)(kc + bk2) * 2048 + (nt << 7) + (bn << 2));
        float4 b1 = *(const float4*)(a.Wms + (long)(kc + bk2 + 8) * 2048 + (nt << 7) + (bn << 2));
        __syncthreads();
        As[(4 * ac + 0) * 132 + am] = a0.x; As[(4 * ac + 1) * 132 + am] = a0.y;
        As[(4 * ac + 2) * 132 + am] = a0.z; As[(4 * ac + 3) * 132 + am] = a0.w;
        As[(4 * ac + 0) * 132 + am + 64] = a1.x; As[(4 * ac + 1) * 132 + am + 64] = a1.y;
        As[(4 * ac + 2) * 132 + am + 64] = a1.z; As[(4 * ac + 3) * 132 + am + 64] = a1.w;
        *(float4*)&Bs[bk2 * 132 + (bn << 2)] = b0;
        *(float4*)&Bs[(bk2 + 8) * 132 + (bn << 2)] = b1;
        __syncthreads();
        #pragma unroll
        for (int kk = 0; kk < 16; ++kk) {
          float4 av0 = *(const float4*)&As[kk * 132 + ty * 4];
          float4 av1 = *(const float4*)&As[kk * 132 + 64 + ty * 4];
          float4 bv0 = *(const float4*)&Bs[kk * 132 + tx * 4];
          float4 bv1 = *(const float4*)&Bs[kk * 132 + 64 + tx * 4];
          float amv[8] = {av0.x, av0.y, av0.z, av0.w, av1.x, av1.y, av1.z, av1.w};
          float bnv[8] = {bv0.x, bv0.y, bv0.z, bv0.w, bv1.x, bv1.y, bv1.z, bv1.w};
          #pragma unroll
          for (int i = 0; i < 8; ++i)
            #pragma unroll
            for (int j = 0; j < 8; ++j)
              acc[i][j] = fmaf(amv[i], bnv[j], acc[i][j]);
        }
      }
      #pragma unroll
      for (int i = 0; i < 8; ++i) {
        int r = ((i >> 2) << 6) + ty * 4 + (i & 3);
        float4 v0 = {acc[i][0], acc[i][1], acc[i][2], acc[i][3]};
        float4 v1 = {acc[i][4], acc[i][5], acc[i][6], acc[i][7]};
        *(float4*)(a.musigP + sp * 262144 + (long)r * 2048 + (nt << 7) + tx * 4) = v0;
        *(float4*)(a.musigP + sp * 262144 + (long)r * 2048 + (nt << 7) + 64 + tx * 4) = v1;
      }
    }
    gridbar(a.bar, bcnt);

    // ============ P4: mu/sig epilogue + noise row `step` ============
    if (gtid < 32768) {
      int b = gtid >> 8, e4 = gtid & 255;
      int e = e4 << 2;
      float4 mu = ((const float4*)a.bmu)[e4];
      float4 sg = ((const float4*)a.bsig)[e4];
      #pragma unroll
      for (int s2 = 0; s2 < 16; ++s2) {
        mu = f4add(mu, ((const float4*)a.musigP)[s2 * 65536 + b * 512 + e4]);
        sg = f4add(sg, ((const float4*)a.musigP)[s2 * 65536 + b * 512 + 256 + e4]);
      }
      sg.x = fmaxf(sg.x, 0.f) + log1pf(expf(-fabsf(sg.x)));
      sg.y = fmaxf(sg.y, 0.f) + log1pf(expf(-fabsf(sg.y)));
      sg.z = fmaxf(sg.z, 0.f) + log1pf(expf(-fabsf(sg.z)));
      sg.w = fmaxf(sg.w, 0.f) + log1pf(expf(-fabsf(sg.w)));
      long off = (long)b * 131072 + (long)step * 1024 + e;
      *(float4*)(a.mus + off) = mu;
      *(float4*)(a.sigs + off) = sg;
      float4 n4 = gen4(sk0, sk1, (unsigned)off);
      float4 out;
      out.x = fmaf(n4.x, sg.x, mu.x); out.y = fmaf(n4.y, sg.y, mu.y);
      out.z = fmaf(n4.z, sg.z, mu.z); out.w = fmaf(n4.w, sg.w, mu.w);
      *(float4*)(a.s + off) = out;
    }
    gridbar(a.bar, bcnt);

    // ============ P5: Q = s_i @ Wq (64-tiles, split-16) ============
    if (bid < 256) {
      float* As = lds;          // [16][68]
      float* Bs = lds + 1088;
      int nt = bid & 7, mt = (bid >> 3) & 1, sp = bid >> 4;
      int kbase = sp << 6;      // Kc=64
      int ar = tid >> 2, ac = tid & 3;
      int br = tid >> 4, bc = tid & 15;
      float acc[4][4];
      #pragma unroll
      for (int i = 0; i < 4; ++i)
        #pragma unroll
        for (int j = 0; j < 4; ++j) acc[i][j] = 0.f;
      for (int c = 0; c < 4; ++c) {
        int kc = kbase + (c << 4);
        float4 a4 = *(const float4*)(a.s + (long)(mt * 64 + ar) * 131072 +
                                     (long)step * 1024 + kc + (ac << 2));
        float4 b4 = *(const float4*)(a.Wq + (long)(kc + br) * 512 + (nt << 6) + (bc << 2));
        __syncthreads();
        As[(4 * ac + 0) * 68 + ar] = a4.x; As[(4 * ac + 1) * 68 + ar] = a4.y;
        As[(4 * ac + 2) * 68 + ar] = a4.z; As[(4 * ac + 3) * 68 + ar] = a4.w;
        *(float4*)&Bs[br * 68 + (bc << 2)] = b4;
        __syncthreads();
        #pragma unroll
        for (int kk = 0; kk < 16; ++kk) {
          float4 av = *(const float4*)&As[kk * 68 + ty * 4];
          float4 bv = *(const float4*)&Bs[kk * 68 + tx * 4];
          float amv[4] = {av.x, av.y, av.z, av.w};
          float bnv[4] = {bv.x, bv.y, bv.z, bv.w};
          #pragma unroll
          for (int im = 0; im < 4; ++im)
            #pragma unroll
            for (int jn = 0; jn < 4; ++jn)
              acc[im][jn] = fmaf(amv[im], bnv[jn], acc[im][jn]);
        }
      }
      #pragma unroll
      for (int im = 0; im < 4; ++im) {
        int b = mt * 64 + ty * 4 + im;
        float4 v = {acc[im][0], acc[im][1], acc[im][2], acc[im][3]};
        *(float4*)(a.qP + sp * 65536 + (long)b * 512 + (nt << 6) + tx * 4) = v;
      }
    }
    gridbar(a.bar, bcnt);

    // ============ P6: t = q @ WkT (+bqk), qb ============
    {
      float* q_l = lds;  // [8][64]
      int eq = bid & 3, hh = (bid >> 2) & 7, bg = bid >> 5;
      int b0 = bg << 3;
      int e = (eq << 8) + tid;
      for (int idx2 = tid; idx2 < 512; idx2 += 256) {
        int bb = idx2 >> 6, aa = idx2 & 63;
        float v = 0.f;
        #pragma unroll
        for (int s2 = 0; s2 < 16; ++s2)
          v += a.qP[s2 * 65536 + (long)(b0 + bb) * 512 + (hh << 6) + aa];
        q_l[bb * 64 + aa] = v;
      }
      __syncthreads();
      float accv[8];
      #pragma unroll
      for (int bb = 0; bb < 8; ++bb) accv[bb] = 0.f;
      for (int aa = 0; aa < 64; ++aa) {
        float wv = a.WkT[(long)((hh << 6) + aa) * 1024 + e];
        #pragma unroll
        for (int bb = 0; bb < 8; ++bb) accv[bb] = fmaf(q_l[bb * 64 + aa], wv, accv[bb]);
      }
      float bq_ = a.bqk[hh * 1024 + e];
      #pragma unroll
      for (int bb = 0; bb < 8; ++bb)
        a.tmat[((long)(b0 + bb) * 8 + hh) * 1024 + e] = accv[bb] + bq_;
      if (eq == 0 && tid < 8) {
        float sm = a.qbc[hh];
        for (int aa = 0; aa < 64; ++aa) sm += q_l[tid * 64 + aa] * a.bk[(hh << 6) + aa];
        a.qbv[(b0 + tid) * 8 + hh] = sm;
      }
    }
    gridbar(a.bar, bcnt);

    // ============ P7: scores ============
    {
      int b = bid >> 2, jt = bid & 3;
      if ((jt << 5) <= step) {
        float* s_ch = lds;          // [32][132]
        float* t_ch = lds + 4224;   // [8][132]
        int jbase = jt << 5;
        int hh = tid >> 5, jj = tid & 31;
        int j = jbase + jj;
        float accv = 0.f;
        for (int e0 = 0; e0 < 1024; e0 += 128) {
          __syncthreads();
          #pragma unroll
          for (int q = 0; q < 4; ++q) {
            int f = tid + (q << 8);
            int jr = f >> 5, e4 = f & 31;
            int jg = jbase + jr;
            if (jg <= step)
              *(float4*)&s_ch[jr * 132 + (e4 << 2)] =
                  *(const float4*)&a.s[(long)b * 131072 + (long)jg * 1024 + e0 + (e4 << 2)];
          }
          {
            int e4 = tid & 31, h2 = tid >> 5;
            *(float4*)&t_ch[h2 * 132 + (e4 << 2)] =
                *(const float4*)&a.tmat[((long)b * 8 + h2) * 1024 + e0 + (e4 << 2)];
          }
          __syncthreads();
          if (j <= step) {
            #pragma unroll
            for (int e4 = 0; e4 < 32; ++e4) {
              float4 sv = *(const float4*)&s_ch[jj * 132 + (e4 << 2)];
              float4 tv = *(const float4*)&t_ch[hh * 132 + (e4 << 2)];
              accv = fmaf(sv.x, tv.x, accv);
              accv = fmaf(sv.y, tv.y, accv);
              accv = fmaf(sv.z, tv.z, accv);
              accv = fmaf(sv.w, tv.w, accv);
            }
          }
        }
        if (j <= step)
          a.scg[((long)b * 8 + hh) * 128 + j] = (accv + a.qbv[b * 8 + hh]) * SCALE_;
      }
    }
    gridbar(a.bar, bcnt);

    // ============ P8: softmax + ctxE (4 jobs/block) ============
    {
      float* w_l = lds;          // [8][128]
      float* s_l = lds + 1024;   // [32][68]
      for (int q2 = 0; q2 < 4; ++q2) {
        int job = (bid << 2) + q2;
        int b = job >> 4, et = job & 15;
        __syncthreads();
        {
          int hh = tid >> 5, l = tid & 31;
          const float* sc = a.scg + ((long)b * 8 + hh) * 128;
          float m = -3.0e38f;
          for (int j = l; j <= step; j += 32) m = fmaxf(m, sc[j]);
          for (int off = 16; off; off >>= 1) m = fmaxf(m, __shfl_xor(m, off, 32));
          float d = 0.f;
          for (int j = l; j <= step; j += 32) {
            float pe = expf(sc[j] - m);
            w_l[hh * 128 + j] = pe;
            d += pe;
          }
          for (int off = 16; off; off >>= 1) d += __shfl_xor(d, off, 32);
          float inv = 1.0f / d;
          for (int j = l; j <= step; j += 32) w_l[hh * 128 + j] *= inv;
        }
        __syncthreads();
        int e = tid & 63, hp = tid >> 6;
        float acc0 = 0.f, acc1 = 0.f;
        for (int jc = 0; jc <= step; jc += 32) {
          __syncthreads();
          #pragma unroll
          for (int q = 0; q < 8; ++q) {
            int f = tid + (q << 8);
            int jr = f >> 6, ee = f & 63;
            int jg = jc + jr;
            if (jg <= step)
              s_l[jr * 68 + ee] = a.s[(long)b * 131072 + (long)jg * 1024 + (et << 6) + ee];
          }
          __syncthreads();
          int jm = min(31, step - jc);
          for (int jr = 0; jr <= jm; ++jr) {
            float sv = s_l[jr * 68 + e];
            acc0 = fmaf(w_l[hp * 128 + jc + jr], sv, acc0);
            acc1 = fmaf(w_l[(hp + 4) * 128 + jc + jr], sv, acc1);
          }
        }
        a.ctxE[((long)b * 8 + hp) * 1024 + (et << 6) + e] = acc0;
        a.ctxE[((long)b * 8 + hp + 4) * 1024 + (et << 6) + e] = acc1;
      }
    }
    gridbar(a.bar, bcnt);

    // ============ P9: V = ctxE @ Wv per head (64-tiles, split-16) ============
    if (bid < 256) {
      float* As = lds;
      float* Bs = lds + 1088;
      int hh = bid & 7, mt = (bid >> 3) & 1, sp = bid >> 4;
      int kbase = sp << 6;  // Kc=64
      int ar = tid >> 2, ac = tid & 3;
      int br = tid >> 4, bc = tid & 15;
      float acc[4][4];
      #pragma unroll
      for (int i = 0; i < 4; ++i)
        #pragma unroll
        for (int j = 0; j < 4; ++j) acc[i][j] = 0.f;
      for (int c = 0; c < 4; ++c) {
        int kc = kbase + (c << 4);
        float4 a4 = *(const float4*)(a.ctxE + ((long)(mt * 64 + ar) * 8 + hh) * 1024 +
                                     kc + (ac << 2));
        float4 b4 = *(const float4*)(a.Wv + (long)(kc + br) * 512 + (hh << 6) + (bc << 2));
        __syncthreads();
        As[(4 * ac + 0) * 68 + ar] = a4.x; As[(4 * ac + 1) * 68 + ar] = a4.y;
        As[(4 * ac + 2) * 68 + ar] = a4.z; As[(4 * ac + 3) * 68 + ar] = a4.w;
        *(float4*)&Bs[br * 68 + (bc << 2)] = b4;
        __syncthreads();
        #pragma unroll
        for (int kk = 0; kk < 16; ++kk) {
          float4 av = *(const float4*)&As[kk * 68 + ty * 4];
          float4 bv = *(const float4*)&Bs[kk * 68 + tx * 4];
          float amv[4] = {av.x, av.y, av.z, av.w};
          float bnv[4] = {bv.x, bv.y, bv.z, bv.w};
          #pragma unroll
          for (int im = 0; im < 4; ++im)
            #pragma unroll
            for (int jn = 0; jn < 4; ++jn)
              acc[im][jn] = fmaf(amv[im], bnv[jn], acc[im][jn]);
        }
      }
      #pragma unroll
      for (int im = 0; im < 4; ++im) {
        int b = mt * 64 + ty * 4 + im;
        float4 v = {acc[im][0], acc[im][1], acc[im][2], acc[im][3]};
        *(float4*)(a.ctxhP + sp * 65536 + (long)b * 512 + (hh << 6) + tx * 4) = v;
      }
    }
    gridbar(a.bar, bcnt);

    // ============ P10: O = ctxh @ Wo (64-tiles, split-4) ============
    if (bid < 128) {
      float* As = lds;
      float* Bs = lds + 1088;
      int ntk = bid & 15, mt = (bid >> 4) & 1, sp = bid >> 5;  // sp 0..3
      int kbase = sp << 7;  // Kc=128
      int ar = tid >> 2, ac = tid & 3;
      int br = tid >> 4, bc = tid & 15;
      float acc[4][4];
      #pragma unroll
      for (int i = 0; i < 4; ++i)
        #pragma unroll
        for (int j = 0; j < 4; ++j) acc[i][j] = 0.f;
      for (int c = 0; c < 8; ++c) {
        int kc = kbase + (c << 4);
        int k = kc + (ac << 2);
        float4 a4;
        a4.x = a4.y = a4.z = a4.w = 0.f;
        #pragma unroll
        for (int s2 = 0; s2 < 16; ++s2)
          a4 = f4add(a4, *(const float4*)(a.ctxhP + s2 * 65536 +
                                          (long)(mt * 64 + ar) * 512 + k));
        float4 b4 = *(const float4*)(a.Wo + (long)(kc + br) * 1024 + (ntk << 6) + (bc << 2));
        __syncthreads();
        As[(4 * ac + 0) * 68 + ar] = a4.x; As[(4 * ac + 1) * 68 + ar] = a4.y;
        As[(4 * ac + 2) * 68 + ar] = a4.z; As[(4 * ac + 3) * 68 + ar] = a4.w;
        *(float4*)&Bs[br * 68 + (bc << 2)] = b4;
        __syncthreads();
        #pragma unroll
        for (int kk = 0; kk < 16; ++kk) {
          float4 av = *(const float4*)&As[kk * 68 + ty * 4];
          float4 bv = *(const float4*)&Bs[kk * 68 + tx * 4];
          float amv[4] = {av.x, av.y, av.z, av.w};
          float bnv[4] = {bv.x, bv.y, bv.z, bv.w};
          #pragma unroll
          for (int im = 0; im < 4; ++im)
            #pragma unroll
            for (int jn = 0; jn < 4; ++jn)
              acc[im][jn] = fmaf(amv[im], bnv[jn], acc[im][jn]);
        }
      }
      #pragma unroll
      for (int im = 0; im < 4; ++im) {
        int b = mt * 64 + ty * 4 + im;
        float4 v = {acc[im][0], acc[im][1], acc[im][2], acc[im][3]};
        *(float4*)(a.ctxvP + sp * 131072 + (long)b * 1024 + (ntk << 6) + tx * 4) = v;
      }
    }
    gridbar(a.bar, bcnt);
  }
}

// ---------------------------------------------------------------------------
// Host side
// ---------------------------------------------------------------------------
extern "C" void kernel_launch(void* const* d_in, const int* in_sizes, int n_in,
                              void* d_out, int out_size, void* d_ws, size_t ws_size,
                              hipStream_t stream) {
  (void)in_sizes; (void)n_in; (void)out_size; (void)ws_size;
  const void* encs  = d_in[0];
  const void* W_ih  = d_in[1];
  const void* W_hh  = d_in[2];
  const void* b_ih  = d_in[3];
  const void* b_hh  = d_in[4];
  const void* W_mu  = d_in[5];
  const void* b_mu  = d_in[6];
  const void* W_sig = d_in[7];
  const void* b_sig = d_in[8];
  const void* W_q   = d_in[9];
  const void* b_q   = d_in[10];
  const void* W_k   = d_in[11];
  const void* b_k   = d_in[12];
  const void* W_v   = d_in[13];
  const void* b_v   = d_in[14];
  const void* W_o   = d_in[15];
  const void* b_o   = d_in[16];

  float* s = (float*)d_out;
  float* w = (float*)d_ws;

  int*      flag = (int*)w;
  unsigned* bar  = (unsigned*)(w + 16);
  float* p     = w + 1024;
  float* WbigF = p;  p += (size_t)2048 * 4096;    // 8.39M
  float* WmsF  = p;  p += (size_t)1024 * 2048;    // 2.10M
  float* WkTF  = p;  p += (size_t)512 * 1024;
  float* WqF   = p;  p += (size_t)1024 * 512;
  float* WvF   = p;  p += (size_t)1024 * 512;
  float* WoF   = p;  p += (size_t)512 * 1024;
  float* encsF = p;  p += (size_t)B_ * E_;
  float* gie4  = p;  p += (size_t)B_ * 4096;      // 0.52M
  float* bihF  = p;  p += 4096;
  float* bhhF  = p;  p += 4096;
  float* bmuF  = p;  p += 1024;
  float* bsigF = p;  p += 1024;
  float* bqF   = p;  p += 1024;
  float* bkF   = p;  p += 1024;
  float* bvF   = p;  p += 1024;
  float* boF   = p;  p += 1024;
  float* bias4 = p;  p += 4096;
  float* bqk   = p;  p += 8192;
  float* qbc   = p;  p += 1024;
  float* bvo   = p;  p += 1024;
  unsigned* skeys = (unsigned*)p; p += 1024;
  float* hbuf  = p;  p += (size_t)B_ * 1024;
  float* qbv   = p;  p += 1024;
  // Region R1 (8.39M): gsumP (P1->P2) ∪ [ctxhP | tmat | ctxE | scg] ∪ Wenc4(prep)
  float* R1    = p;  p += (size_t)16 * 524288;
  float* gsumP = R1;
  float* ctxhP = R1;                         // 16*65536 = 1.05M  (P9->P10)
  float* tmat  = R1 + 1048576;               // 1.05M             (P6->P7)
  float* ctxE  = R1 + 2097152;               // 1.05M             (P8->P9)
  float* scg   = R1 + 3145728;               // 0.13M             (P7->P8)
  float* Wenc4 = R1 + 4194304;               // 4.19M, prep only
  // Region R2 (4.19M): musigP (P3->P4) ∪ qP (P5->P6) ∪ ctxvP (P10->next P1)
  float* R2    = p;  p += (size_t)16 * 262144;
  float* musigP = R2;
  float* qP     = R2;                        // 16*65536
  float* ctxvP  = R2;                        // 4*131072
  float* mus   = p;  p += (size_t)B_ * T_ * E_;   // 16.8M
  float* sigs  = p;  p += (size_t)B_ * T_ * E_;   // 16.8M
  // total ≈ 58.6M floats ≈ 235 MB

  // ---- prep ----
  sniff_kernel<<<1, 256, 0, stream>>>(encs, flag);
  auto conv = [&](const void* src, float* dst, long n) {
    conv_kernel<<<dim3((unsigned)((n + 255) / 256)), 256, 0, stream>>>(src, dst, n, flag);
  };
  conv(encs,  encsF, (long)B_ * E_);
  conv(b_ih,  bihF,  G_);
  conv(b_hh,  bhhF,  G_);
  conv(b_mu,  bmuF,  1024);
  conv(b_sig, bsigF, 1024);
  conv(b_q,   bqF,   512);
  conv(b_k,   bkF,   512);
  conv(b_v,   bvF,   512);
  conv(b_o,   boF,   1024);
  conv(W_q,   WqF,   (long)1024 * 512);
  conv(W_v,   WvF,   (long)1024 * 512);
  conv(W_o,   WoF,   (long)512 * 1024);

  trans_kernel<<<dim3(16384, 5), 256, 0, stream>>>(
      W_ih, W_hh, W_mu, W_sig, W_k, bihF, bhhF,
      WbigF, WmsF, WkTF, Wenc4, bias4, hbuf, skeys, bar, flag);
  consts_kernel<<<dim3(32), 256, 0, stream>>>(
      bqF, bkF, bvF, boF, WkTF, WoF, bqk, qbc, bvo);
  // gie4 = encs @ Wenc4 (reads Wenc4 inside R1 before scan clobbers it)
  mm128<<<dim3(32, 1, 1), 256, 0, stream>>>(encsF, 1024, Wenc4, 4096, gie4, 4096, 1024);

  // ---- persistent scan (1 launch, 512 co-resident blocks) ----
  SArgs sa;
  sa.Wbig = WbigF; sa.Wms = WmsF; sa.WkT = WkTF; sa.Wq = WqF; sa.Wv = WvF; sa.Wo = WoF;
  sa.gie4 = gie4; sa.bias4 = bias4; sa.bqk = bqk; sa.qbc = qbc; sa.bvo = bvo;
  sa.bmu = bmuF; sa.bsig = bsigF; sa.bk = bkF; sa.skeys = skeys;
  sa.hbuf = hbuf; sa.gsumP = gsumP; sa.musigP = musigP; sa.qP = qP; sa.tmat = tmat;
  sa.qbv = qbv; sa.scg = scg; sa.ctxE = ctxE; sa.ctxhP = ctxhP; sa.ctxvP = ctxvP;
  sa.mus = mus; sa.sigs = sigs; sa.s = s; sa.bar = bar;
  scan_kernel<<<dim3(NB), dim3(NT), 0, stream>>>(sa);
  // d_out == s holds the step-127 sample (same fold_in(key,127) as eps_last)
}